// Round 1
// baseline (110.661 us; speedup 1.0000x reference)
//
#include <hip/hip_runtime.h>

#define BATCH 64
#define IN_F 512
#define OUT_F 512
#define BASIS 8

// Kernel 1: per (b,i) compute silu(x) and Chebyshev T_1..T_8(tanh(x)).
// T_k(t) = cos(k*arccos(t)) exactly -> use recurrence, no acos/cos.
// Layouts chosen for kernel-2 coalescing:
//   actS[i*64 + b]            (lane = b -> stride-4B coalesced)
//   actT[(i*64 + b)*8 + k]    (lane = b -> 2x float4 per lane, 2KB/wave contiguous)
__global__ __launch_bounds__(256) void kan_prep(const float* __restrict__ x,
                                                float* __restrict__ actS,
                                                float* __restrict__ actT) {
    int tid = blockIdx.x * 256 + threadIdx.x;   // 0 .. 32767
    int b = tid & (BATCH - 1);
    int i = tid >> 6;
    float xv = x[b * IN_F + i];
    float sl = xv / (1.0f + expf(-xv));         // silu
    float t = tanhf(xv);
    t = fminf(fmaxf(t, -1.0f + 1e-6f), 1.0f - 1e-6f);
    // T0 = 1, T1 = t, T_{k+1} = 2t*T_k - T_{k-1}; store T1..T8
    float T1 = t;
    float T2 = 2.0f * t * T1 - 1.0f;
    float T3 = 2.0f * t * T2 - T1;
    float T4 = 2.0f * t * T3 - T2;
    float T5 = 2.0f * t * T4 - T3;
    float T6 = 2.0f * t * T5 - T4;
    float T7 = 2.0f * t * T6 - T5;
    float T8 = 2.0f * t * T7 - T6;
    actS[i * BATCH + b] = sl;
    float4* dst = (float4*)(actT + (size_t)(i * BATCH + b) * BASIS);
    dst[0] = make_float4(T1, T2, T3, T4);
    dst[1] = make_float4(T5, T6, T7, T8);
}

// Kernel 2: out[b,o] = sum_i w[i,o] * (silu_bi + sum_k T_k(b,i)*c[i,o,k])
// Grid: 32 o-tiles (16 o each) x 16 i-chunks (32 i each) = 512 blocks.
// Block: 256 threads; lane b = tid&63, o-group og = tid>>6 (wave-uniform),
// each thread owns 4 consecutive o. c/w loads are wave-uniform broadcasts.
__global__ __launch_bounds__(256) void kan_main(const float* __restrict__ actS,
                                                const float* __restrict__ actT,
                                                const float* __restrict__ w,
                                                const float* __restrict__ c,
                                                float* __restrict__ out) {
    int otile  = blockIdx.x & 31;   // 0..31
    int ichunk = blockIdx.x >> 5;   // 0..15
    int tid = threadIdx.x;
    int b  = tid & 63;
    int og = tid >> 6;              // 0..3, wave-uniform
    int obase = otile * 16 + og * 4;

    float acc0 = 0.f, acc1 = 0.f, acc2 = 0.f, acc3 = 0.f;
    int i0 = ichunk * 32;

    for (int ii = 0; ii < 32; ++ii) {
        int i = i0 + ii;
        float sl = actS[i * BATCH + b];
        const float4* tp = (const float4*)(actT + (size_t)(i * BATCH + b) * BASIS);
        float4 ta = tp[0];
        float4 tb = tp[1];
        float4 wv = *(const float4*)(w + (size_t)i * OUT_F + obase);
        const float4* cp = (const float4*)(c + ((size_t)i * OUT_F + obase) * BASIS);

        // o = obase + 0
        {
            float4 c0 = cp[0], c1 = cp[1];
            float s = ta.x * c0.x;
            s = fmaf(ta.y, c0.y, s); s = fmaf(ta.z, c0.z, s); s = fmaf(ta.w, c0.w, s);
            s = fmaf(tb.x, c1.x, s); s = fmaf(tb.y, c1.y, s); s = fmaf(tb.z, c1.z, s);
            s = fmaf(tb.w, c1.w, s);
            acc0 = fmaf(wv.x, sl + s, acc0);
        }
        // o = obase + 1
        {
            float4 c0 = cp[2], c1 = cp[3];
            float s = ta.x * c0.x;
            s = fmaf(ta.y, c0.y, s); s = fmaf(ta.z, c0.z, s); s = fmaf(ta.w, c0.w, s);
            s = fmaf(tb.x, c1.x, s); s = fmaf(tb.y, c1.y, s); s = fmaf(tb.z, c1.z, s);
            s = fmaf(tb.w, c1.w, s);
            acc1 = fmaf(wv.y, sl + s, acc1);
        }
        // o = obase + 2
        {
            float4 c0 = cp[4], c1 = cp[5];
            float s = ta.x * c0.x;
            s = fmaf(ta.y, c0.y, s); s = fmaf(ta.z, c0.z, s); s = fmaf(ta.w, c0.w, s);
            s = fmaf(tb.x, c1.x, s); s = fmaf(tb.y, c1.y, s); s = fmaf(tb.z, c1.z, s);
            s = fmaf(tb.w, c1.w, s);
            acc2 = fmaf(wv.z, sl + s, acc2);
        }
        // o = obase + 3
        {
            float4 c0 = cp[6], c1 = cp[7];
            float s = ta.x * c0.x;
            s = fmaf(ta.y, c0.y, s); s = fmaf(ta.z, c0.z, s); s = fmaf(ta.w, c0.w, s);
            s = fmaf(tb.x, c1.x, s); s = fmaf(tb.y, c1.y, s); s = fmaf(tb.z, c1.z, s);
            s = fmaf(tb.w, c1.w, s);
            acc3 = fmaf(wv.w, sl + s, acc3);
        }
    }

    float* op = out + (size_t)b * OUT_F + obase;
    atomicAdd(op + 0, acc0);
    atomicAdd(op + 1, acc1);
    atomicAdd(op + 2, acc2);
    atomicAdd(op + 3, acc3);
}

extern "C" void kernel_launch(void* const* d_in, const int* in_sizes, int n_in,
                              void* d_out, int out_size, void* d_ws, size_t ws_size,
                              hipStream_t stream) {
    const float* x = (const float*)d_in[0];   // (64, 512)
    const float* w = (const float*)d_in[1];   // (512, 512)
    const float* c = (const float*)d_in[2];   // (512, 512, 8)
    float* out = (float*)d_out;               // (64, 512) fp32

    float* actS = (float*)d_ws;                    // 64*512 floats = 128 KB
    float* actT = actS + (size_t)BATCH * IN_F;     // 64*512*8 floats = 1 MB

    // out is poisoned before every call; atomics need zeros.
    hipMemsetAsync(d_out, 0, (size_t)out_size * sizeof(float), stream);

    kan_prep<<<(BATCH * IN_F) / 256, 256, 0, stream>>>(x, actS, actT);
    kan_main<<<512, 256, 0, stream>>>(actS, actT, w, c, out);
}

// Round 2
// 96.263 us; speedup vs baseline: 1.1496x; 1.1496x over previous
//
#include <hip/hip_runtime.h>

#define BATCH 64
#define IN_F 512
#define OUT_F 512
#define BASIS 8
#define NSPLIT 64   // i-chunks of 8

// ---------------------------------------------------------------------------
// Kernel 1: per (b,i) compute silu(x) and Chebyshev T_1..T_8(tanh(x)).
// T_k(t) = cos(k*arccos(t)) -> 2-term recurrence, no transcendental loop.
// tanh via e^{-x}: tanh(x) = (1-u^2)/(1+u^2), u = e^{-x}; silu = x/(1+u).
// Layout [b][i] so prep reads AND writes are lane-coalesced (lane = i), and
// kan_main's per-(b,i) reads are wave-uniform scalar loads.
// ---------------------------------------------------------------------------
__global__ __launch_bounds__(512) void kan_prep(const float* __restrict__ x,
                                                float* __restrict__ actS,
                                                float* __restrict__ actT) {
    int b = blockIdx.x;        // 0..63
    int i = threadIdx.x;       // 0..511
    float xv = x[b * IN_F + i];
    float xc = fminf(fmaxf(xv, -15.f), 15.f);   // keep u^2 finite
    float u  = expf(-xc);
    float sl = xv / (1.0f + u);                 // silu(x)
    float u2 = u * u;
    float t  = (1.0f - u2) / (1.0f + u2);       // tanh(x)
    t = fminf(fmaxf(t, -1.0f + 1e-6f), 1.0f - 1e-6f);
    float T1 = t;
    float T2 = 2.0f * t * T1 - 1.0f;
    float T3 = 2.0f * t * T2 - T1;
    float T4 = 2.0f * t * T3 - T2;
    float T5 = 2.0f * t * T4 - T3;
    float T6 = 2.0f * t * T5 - T4;
    float T7 = 2.0f * t * T6 - T5;
    float T8 = 2.0f * t * T7 - T6;
    actS[b * IN_F + i] = sl;
    float4* dst = (float4*)(actT + ((size_t)b * IN_F + i) * BASIS);
    dst[0] = make_float4(T1, T2, T3, T4);   // lane=i -> stride 32B, coalesced
    dst[1] = make_float4(T5, T6, T7, T8);
}

// ---------------------------------------------------------------------------
// Kernel 2: partial[b,o] over an i-chunk of 8.
// lane -> o (c[i][o][k] contiguous 32B per lane => 2KB/wave coalesced loads),
// wave -> 16 b's per thread as accumulators; T/silu are wave-uniform scalar
// loads (SGPR operands into v_fma). 512 blocks = 2048 waves = 8 waves/CU.
// Plain coalesced stores to ws (no atomics -> no L2 write-through storm).
// ---------------------------------------------------------------------------
__global__ __launch_bounds__(256) void kan_main(const float* __restrict__ actS,
                                                const float* __restrict__ actT,
                                                const float* __restrict__ w,
                                                const float* __restrict__ c,
                                                float* __restrict__ partial) {
    int otile  = blockIdx.x & 7;    // 8 o-tiles of 64
    int ichunk = blockIdx.x >> 3;   // 0..63, i-chunks of 8
    int lane   = threadIdx.x & 63;
    int wid    = __builtin_amdgcn_readfirstlane(threadIdx.x >> 6); // 0..3
    int o  = otile * 64 + lane;
    int b0 = wid * 16;
    int i0 = ichunk * 8;

    float acc[16];
#pragma unroll
    for (int j = 0; j < 16; ++j) acc[j] = 0.f;

#pragma unroll 4
    for (int ii = 0; ii < 8; ++ii) {
        int i = i0 + ii;
        const float4* cp = (const float4*)(c + ((size_t)i * OUT_F + o) * BASIS);
        float4 c0 = cp[0];
        float4 c1 = cp[1];
        float wv = w[(size_t)i * OUT_F + o];
#pragma unroll
        for (int bb = 0; bb < 16; ++bb) {
            const float* Tp = actT + ((size_t)(b0 + bb) * IN_F + i) * BASIS; // uniform
            float sl = actS[(size_t)(b0 + bb) * IN_F + i];                    // uniform
            float s = c0.x * Tp[0];
            s = fmaf(c0.y, Tp[1], s);
            s = fmaf(c0.z, Tp[2], s);
            s = fmaf(c0.w, Tp[3], s);
            s = fmaf(c1.x, Tp[4], s);
            s = fmaf(c1.y, Tp[5], s);
            s = fmaf(c1.z, Tp[6], s);
            s = fmaf(c1.w, Tp[7], s);
            acc[bb] = fmaf(wv, sl + s, acc[bb]);
        }
    }

    float* pp = partial + ((size_t)ichunk * BATCH + b0) * OUT_F + o;
#pragma unroll
    for (int bb = 0; bb < 16; ++bb) pp[(size_t)bb * OUT_F] = acc[bb];
}

// ---------------------------------------------------------------------------
// Kernel 3: out[b,o] = sum over 64 i-chunk partials. Fully coalesced.
// Writes every out element -> no memset of d_out needed.
// ---------------------------------------------------------------------------
__global__ __launch_bounds__(256) void kan_reduce(const float* __restrict__ partial,
                                                  float* __restrict__ out) {
    int idx = blockIdx.x * 256 + threadIdx.x;   // 0..32767 = b*512+o
    float a0 = 0.f, a1 = 0.f, a2 = 0.f, a3 = 0.f;
#pragma unroll
    for (int s = 0; s < NSPLIT; s += 4) {
        a0 += partial[(size_t)(s + 0) * (BATCH * OUT_F) + idx];
        a1 += partial[(size_t)(s + 1) * (BATCH * OUT_F) + idx];
        a2 += partial[(size_t)(s + 2) * (BATCH * OUT_F) + idx];
        a3 += partial[(size_t)(s + 3) * (BATCH * OUT_F) + idx];
    }
    out[idx] = (a0 + a1) + (a2 + a3);
}

extern "C" void kernel_launch(void* const* d_in, const int* in_sizes, int n_in,
                              void* d_out, int out_size, void* d_ws, size_t ws_size,
                              hipStream_t stream) {
    const float* x = (const float*)d_in[0];   // (64, 512)
    const float* w = (const float*)d_in[1];   // (512, 512)
    const float* c = (const float*)d_in[2];   // (512, 512, 8)
    float* out = (float*)d_out;               // (64, 512) fp32

    float* actS    = (float*)d_ws;                           // 128 KB
    float* actT    = actS + (size_t)BATCH * IN_F;            // 1 MB
    float* partial = actT + (size_t)BATCH * IN_F * BASIS;    // 8 MB

    kan_prep<<<BATCH, 512, 0, stream>>>(x, actS, actT);
    kan_main<<<8 * NSPLIT, 256, 0, stream>>>(actS, actT, w, c, partial);
    kan_reduce<<<(BATCH * OUT_F) / 256, 256, 0, stream>>>(partial, out);
}

// Round 4
// 91.594 us; speedup vs baseline: 1.2082x; 1.0510x over previous
//
#include <hip/hip_runtime.h>

#define BATCH 64
#define IN_F 512
#define OUT_F 512
#define BASIS 8
#define OC_W 16            // o's per block
#define IC_W 32            // i's per block (4 waves x 8)
#define NOC (OUT_F / OC_W) // 32
#define NIC (IN_F / IC_W)  // 16

// ---------------------------------------------------------------------------
// Fused kernel. Grid = 32 o-chunks x 16 i-chunks = 512 blocks, 256 thr.
// lane = b: T1..T8/silu computed inline per-lane in VGPRs (no LDS broadcast).
// c/w rows are wave-uniform (blockIdx + readfirstlane(wid)) over
// const __restrict__ => compiler emits s_load streams; FMAs take the c
// operand from SGPRs (1 scalar operand per VALU op - legal).
// 4 waves split the 32 i's; cross-wave LDS reduce; coalesced partial store.
// ---------------------------------------------------------------------------
__global__ __launch_bounds__(256, 2) void kan_main(const float* __restrict__ x,
                                                   const float* __restrict__ w,
                                                   const float* __restrict__ c,
                                                   float* __restrict__ partial) {
    __shared__ float x_lds[IC_W * BATCH];        // [ii][b]  8 KB
    __shared__ float r_lds[4 * BATCH * OC_W];    // [wid][b][oo] 16 KB

    int oc  = blockIdx.x & (NOC - 1);
    int ic  = blockIdx.x >> 5;
    int tid = threadIdx.x;
    int lane = tid & 63;
    int wid  = __builtin_amdgcn_readfirstlane(tid >> 6);   // 0..3, uniform

    // ---- stage x tile [64 b][32 i] -> x_lds[ii][b] (one-shot transpose) ----
    {
        int c4   = tid & 7;        // float4 index within a 32-float row
        int brow = tid >> 3;       // 0..31
#pragma unroll
        for (int h = 0; h < 2; ++h) {
            int b = brow + 32 * h;
            float4 xv = *(const float4*)(x + (size_t)b * IN_F + ic * IC_W + c4 * 4);
            x_lds[(c4 * 4 + 0) * BATCH + b] = xv.x;
            x_lds[(c4 * 4 + 1) * BATCH + b] = xv.y;
            x_lds[(c4 * 4 + 2) * BATCH + b] = xv.z;
            x_lds[(c4 * 4 + 3) * BATCH + b] = xv.w;
        }
    }
    __syncthreads();

    float acc[OC_W];
#pragma unroll
    for (int j = 0; j < OC_W; ++j) acc[j] = 0.f;

    int ibase = ic * IC_W + wid * 8;

#pragma unroll
    for (int ii = 0; ii < 8; ++ii) {
        int i = ibase + ii;
        float xv = x_lds[(wid * 8 + ii) * BATCH + lane];   // dense, conflict-free

        // ---- activations in registers (per-lane b) ----
        float xc = fminf(fmaxf(xv, -15.f), 15.f);
        float u  = __expf(-xc);
        float sl = __fdividef(xv, 1.0f + u);               // silu(x)
        float u2 = u * u;
        float t  = __fdividef(1.0f - u2, 1.0f + u2);       // tanh(x)
        t = fminf(fmaxf(t, -1.0f + 1e-6f), 1.0f - 1e-6f);
        float t2x = t + t;
        float T1 = t;
        float T2 = fmaf(t2x, T1, -1.0f);
        float T3 = fmaf(t2x, T2, -T1);
        float T4 = fmaf(t2x, T3, -T2);
        float T5 = fmaf(t2x, T4, -T3);
        float T6 = fmaf(t2x, T5, -T4);
        float T7 = fmaf(t2x, T6, -T5);
        float T8 = fmaf(t2x, T7, -T6);

        // ---- uniform c/w rows -> scalar loads ----
        const float* crow = c + ((size_t)i * OUT_F + oc * OC_W) * BASIS; // 128 fl
        const float* wrow = w + (size_t)i * OUT_F + oc * OC_W;           // 16 fl

#pragma unroll 4
        for (int oo = 0; oo < OC_W; ++oo) {
            const float* cp = crow + oo * 8;
            float s = cp[0] * T1;
            s = fmaf(cp[1], T2, s);
            s = fmaf(cp[2], T3, s);
            s = fmaf(cp[3], T4, s);
            s = fmaf(cp[4], T5, s);
            s = fmaf(cp[5], T6, s);
            s = fmaf(cp[6], T7, s);
            s = fmaf(cp[7], T8, s);
            acc[oo] = fmaf(wrow[oo], sl + s, acc[oo]);
        }
    }

    // ---- cross-wave reduce (4 waves hold disjoint i-ranges of same (b,o)) ----
#pragma unroll
    for (int j = 0; j < OC_W; j += 4)
        *(float4*)&r_lds[(wid * BATCH + lane) * OC_W + j] =
            make_float4(acc[j], acc[j + 1], acc[j + 2], acc[j + 3]);
    __syncthreads();

    // q = b*16 + oo in 0..1023; sum the 4 wave segments; coalesced store.
    float* pf = partial + ((size_t)ic * NOC + oc) * (BATCH * OC_W);
#pragma unroll
    for (int rep = 0; rep < 4; ++rep) {
        int q = rep * 256 + tid;
        float v = (r_lds[q] + r_lds[1024 + q]) + (r_lds[2048 + q] + r_lds[3072 + q]);
        pf[q] = v;
    }
}

// ---------------------------------------------------------------------------
// out[b,o] = sum over 16 i-chunk partials. partial[ic][oc][b*16+oo], 2 MB.
// Writes every out element -> no memset needed.
// ---------------------------------------------------------------------------
__global__ __launch_bounds__(256) void kan_reduce(const float* __restrict__ partial,
                                                  float* __restrict__ out) {
    int g  = blockIdx.x * 256 + threadIdx.x;   // 0..32767 = b*512 + o
    int b  = g >> 9;
    int o  = g & (OUT_F - 1);
    int oc = o >> 4;
    int oo = o & (OC_W - 1);
    const float* p = partial + (size_t)oc * (BATCH * OC_W) + b * OC_W + oo;
    float s = 0.f;
#pragma unroll
    for (int icx = 0; icx < NIC; ++icx)
        s += p[(size_t)icx * (NOC * BATCH * OC_W)];
    out[g] = s;
}

extern "C" void kernel_launch(void* const* d_in, const int* in_sizes, int n_in,
                              void* d_out, int out_size, void* d_ws, size_t ws_size,
                              hipStream_t stream) {
    const float* x = (const float*)d_in[0];   // (64, 512)
    const float* w = (const float*)d_in[1];   // (512, 512)
    const float* c = (const float*)d_in[2];   // (512, 512, 8)
    float* out = (float*)d_out;               // (64, 512) fp32

    float* partial = (float*)d_ws;            // 16*32*1024 floats = 2 MB

    kan_main<<<NOC * NIC, 256, 0, stream>>>(x, w, c, partial);
    kan_reduce<<<(BATCH * OUT_F) / 256, 256, 0, stream>>>(partial, out);
}

// Round 5
// 71.871 us; speedup vs baseline: 1.5397x; 1.2744x over previous
//
#include <hip/hip_runtime.h>

#define BATCH 64
#define IN_F 512
#define OUT_F 512
#define NKS 32             // K-split: 32 blocks of 16 i's
#define ICH 16             // i's per block
#define NNS 16             // N-split: 16 o-tiles of 32

typedef short short8 __attribute__((ext_vector_type(8)));
typedef float f32x4 __attribute__((ext_vector_type(4)));

// pack two fp32 -> packed bf16 pair (round-half-up via +0x8000, then v_perm
// grabs the two high halves). low16 = bf16(a), high16 = bf16(b).
static __device__ __forceinline__ unsigned bfpk(float a, float b) {
    unsigned ua = __float_as_uint(a) + 0x8000u;
    unsigned ub = __float_as_uint(b) + 0x8000u;
    return __builtin_amdgcn_perm(ub, ua, 0x07060302u);
}

// ---------------------------------------------------------------------------
// Prep: per (b,i) compute T1..T8(tanh x) and silu(x), store as bf16.
// A_c layout [(i*64+b)*8]: exactly the 16x16x32 A-fragment order
//   (lane m=lane&15 -> b, quad -> i within K-step, j -> T_{j+1}).
// A_s layout [b*512+i]: contiguous 8-slot rows for the silu*w K-step.
// ---------------------------------------------------------------------------
__global__ __launch_bounds__(256) void kan_prep(const float* __restrict__ x,
                                                short* __restrict__ A_c,
                                                short* __restrict__ A_s) {
    int gid = blockIdx.x * 256 + threadIdx.x;   // 0..32767
    int i = gid & (IN_F - 1);
    int b = gid >> 9;
    float xv = x[b * IN_F + i];
    float xc = fminf(fmaxf(xv, -15.f), 15.f);
    float u  = __expf(-xc);
    float sl = __fdividef(xv, 1.0f + u);            // silu
    float u2 = u * u;
    float t  = __fdividef(1.0f - u2, 1.0f + u2);    // tanh
    t = fminf(fmaxf(t, -1.0f + 1e-6f), 1.0f - 1e-6f);
    float t2 = t + t;
    float T1 = t;
    float T2 = fmaf(t2, T1, -1.0f);
    float T3 = fmaf(t2, T2, -T1);
    float T4 = fmaf(t2, T3, -T2);
    float T5 = fmaf(t2, T4, -T3);
    float T6 = fmaf(t2, T5, -T4);
    float T7 = fmaf(t2, T6, -T5);
    float T8 = fmaf(t2, T7, -T6);
    union { short8 v; unsigned u4[4]; } fr;
    fr.u4[0] = bfpk(T1, T2);
    fr.u4[1] = bfpk(T3, T4);
    fr.u4[2] = bfpk(T5, T6);
    fr.u4[3] = bfpk(T7, T8);
    *(short8*)(A_c + ((size_t)i * BATCH + b) * 8) = fr.v;
    A_s[(size_t)b * IN_F + i] = (short)(bfpk(sl, 0.f) & 0xffffu);
}

// ---------------------------------------------------------------------------
// MFMA GEMM: out = A(64 x K) @ B(K x 512), K = 512*8 (T*wc) + 512 (silu*w).
// Grid = 32 Ksplit x 16 Nsplit = 512 blocks; 4 waves = 4 b-tiles of 16.
// Per wave: 4 c-steps (i-chunk 16 = 4 i per 32-K step; quad -> i, j -> k)
// + 1 w-step (16 silu slots in quads 0/1). B built in-register:
// lane's c-row = 32B contiguous float4x2 (c read exactly once device-wide).
// ---------------------------------------------------------------------------
__global__ __launch_bounds__(256, 2) void kan_mfma(const short* __restrict__ A_c,
                                                   const short* __restrict__ A_s,
                                                   const float* __restrict__ w,
                                                   const float* __restrict__ c,
                                                   float* __restrict__ partial) {
    int nb   = blockIdx.x & (NNS - 1);
    int kb   = blockIdx.x >> 4;
    int lane = threadIdx.x & 63;
    int wid  = threadIdx.x >> 6;     // b-tile
    int m    = lane & 15;
    int quad = lane >> 4;
    int b    = wid * 16 + m;
    int i0   = kb * ICH;

    // A fragments (T-part): step s covers i = i0 + s*4 + quad, k=j -> T_{j+1}
    short8 af[4];
#pragma unroll
    for (int s = 0; s < 4; ++s)
        af[s] = *(const short8*)(A_c + ((size_t)(i0 + s * 4 + quad) * BATCH + b) * 8);
    // A fragment (silu-part): slots s2 = quad*8+j, valid s2 < 16
    short8 awf = short8{0, 0, 0, 0, 0, 0, 0, 0};
    if (quad < 2)
        awf = *(const short8*)(A_s + (size_t)b * IN_F + i0 + quad * 8);

#pragma unroll
    for (int nf = 0; nf < 2; ++nf) {
        int o = nb * 32 + nf * 16 + m;   // n = lane&15
        f32x4 acc = {0.f, 0.f, 0.f, 0.f};
#pragma unroll
        for (int s = 0; s < 4; ++s) {
            int i = i0 + s * 4 + quad;
            const float4* cp = (const float4*)(c + ((size_t)i * OUT_F + o) * 8);
            float4 c0 = cp[0];
            float4 c1 = cp[1];
            float wv = w[(size_t)i * OUT_F + o];
            union { short8 v; unsigned u4[4]; } bf;
            bf.u4[0] = bfpk(wv * c0.x, wv * c0.y);
            bf.u4[1] = bfpk(wv * c0.z, wv * c0.w);
            bf.u4[2] = bfpk(wv * c1.x, wv * c1.y);
            bf.u4[3] = bfpk(wv * c1.z, wv * c1.w);
            acc = __builtin_amdgcn_mfma_f32_16x16x32_bf16(af[s], bf.v, acc, 0, 0, 0);
        }
        // silu*w K-step: B[s2][n] = w[i0+s2][o], s2 < 16
        union { short8 v; unsigned u4[4]; } bw;
        if (quad < 2) {
            const float* wp = w + (size_t)(i0 + quad * 8) * OUT_F + o;
            bw.u4[0] = bfpk(wp[0 * OUT_F], wp[1 * OUT_F]);
            bw.u4[1] = bfpk(wp[2 * OUT_F], wp[3 * OUT_F]);
            bw.u4[2] = bfpk(wp[4 * OUT_F], wp[5 * OUT_F]);
            bw.u4[3] = bfpk(wp[6 * OUT_F], wp[7 * OUT_F]);
        } else {
            bw.u4[0] = bw.u4[1] = bw.u4[2] = bw.u4[3] = 0u;
        }
        acc = __builtin_amdgcn_mfma_f32_16x16x32_bf16(awf, bw.v, acc, 0, 0, 0);

        // C/D: row = quad*4 + reg (b), col = lane&15 (o)  [m89-verified]
        float* pp = partial + ((size_t)kb * BATCH + wid * 16 + quad * 4) * OUT_F + o;
#pragma unroll
        for (int r = 0; r < 4; ++r) pp[(size_t)r * OUT_F] = acc[r];
    }
}

// ---------------------------------------------------------------------------
// out[b,o] = sum over 32 K-split partials. Fully coalesced, writes all of out.
// ---------------------------------------------------------------------------
__global__ __launch_bounds__(256) void kan_reduce(const float* __restrict__ partial,
                                                  float* __restrict__ out) {
    int g = blockIdx.x * 256 + threadIdx.x;   // 0..32767
    float a0 = 0.f, a1 = 0.f, a2 = 0.f, a3 = 0.f;
#pragma unroll
    for (int s = 0; s < NKS; s += 4) {
        a0 += partial[(size_t)(s + 0) * (BATCH * OUT_F) + g];
        a1 += partial[(size_t)(s + 1) * (BATCH * OUT_F) + g];
        a2 += partial[(size_t)(s + 2) * (BATCH * OUT_F) + g];
        a3 += partial[(size_t)(s + 3) * (BATCH * OUT_F) + g];
    }
    out[g] = (a0 + a1) + (a2 + a3);
}

extern "C" void kernel_launch(void* const* d_in, const int* in_sizes, int n_in,
                              void* d_out, int out_size, void* d_ws, size_t ws_size,
                              hipStream_t stream) {
    const float* x = (const float*)d_in[0];   // (64, 512)
    const float* w = (const float*)d_in[1];   // (512, 512)
    const float* c = (const float*)d_in[2];   // (512, 512, 8)
    float* out = (float*)d_out;               // (64, 512) fp32

    short* A_c = (short*)d_ws;                              // 512 KB
    short* A_s = A_c + (size_t)IN_F * BATCH * 8;            // 64 KB
    float* partial = (float*)((char*)d_ws + 589824);        // 4 MB, 16B-aligned

    kan_prep<<<(BATCH * IN_F) / 256, 256, 0, stream>>>(x, A_c, A_s);
    kan_mfma<<<NKS * NNS, 256, 0, stream>>>(A_c, A_s, w, c, partial);
    kan_reduce<<<(BATCH * OUT_F) / 256, 256, 0, stream>>>(partial, out);
}